// Round 7
// baseline (401.789 us; speedup 1.0000x reference)
//
#include <hip/hip_runtime.h>
#include <hip/hip_bf16.h>
#include <math.h>

// LlamaStyleAttention: B=2, T=2048, C=2048, H=16, D=128, fp32 in/out.
// R7: attn rebuilt with GEMM-style pipeline discipline — triple-buffered K/V,
//     raw s_barrier + counted vmcnt (no __syncthreads vmcnt(0) drains),
//     V chunk swizzle fixed to cap PV LDS reads at 2-way conflicts.
//     GEMMs (k_g8 128x384 / 128x256) and aux unchanged from R6.

#define TT 2048
#define CCn 2048
#define HH 16
#define DD 128
#define MMr 4096   // B*T
#define NQKV 6144  // 3*C

typedef __attribute__((ext_vector_type(8))) short s16x8;
typedef __attribute__((ext_vector_type(4))) short s16x4;
typedef __attribute__((ext_vector_type(4))) float f32x4;

__device__ __forceinline__ short bf16_of(float f) {
  unsigned u = __float_as_uint(f);
  unsigned r = u + 0x7fffu + ((u >> 16) & 1u);
  return (short)(r >> 16);
}
__device__ __forceinline__ float f_of_bf16(short s) {
  return __uint_as_float(((unsigned)(unsigned short)s) << 16);
}
__device__ __forceinline__ float ex2(float x) { return exp2f(x); }

__device__ __forceinline__ void lds_load16(const void* g, void* l) {
  __builtin_amdgcn_global_load_lds((__attribute__((address_space(1))) void*)g,
                                   (__attribute__((address_space(3))) void*)l,
                                   16, 0, 0);
}

// ---------------- cos/sin tables: [T][64] fp32 ----------------
__global__ __launch_bounds__(256) void k_tables(float* __restrict__ cosT,
                                                float* __restrict__ sinT) {
  int idx = blockIdx.x * 256 + threadIdx.x;
  int t = idx >> 6, i = idx & 63;
  float inv = powf(10000.0f, -(float)i * (1.0f / 64.0f));
  float f = (float)t * inv;
  cosT[idx] = cosf(f);
  sinT[idx] = sinf(f);
}

// ---------------- x fp32 -> bf16 ----------------
__global__ __launch_bounds__(256) void k_cast_x(const float* __restrict__ x,
                                                short* __restrict__ xb) {
  int i = blockIdx.x * 256 + threadIdx.x;
  f32x4 v = ((const f32x4*)x)[i];
  s16x4 o;
#pragma unroll
  for (int j = 0; j < 4; ++j) o[j] = bf16_of(v[j]);
  ((s16x4*)xb)[i] = o;
}

// ------------- weight transpose+cast (all 4 weights, z-indexed) -------------
__global__ __launch_bounds__(256) void k_wtrans4(const float* __restrict__ w0,
                                                 const float* __restrict__ w1,
                                                 const float* __restrict__ w2,
                                                 const float* __restrict__ w3,
                                                 short* __restrict__ wqkvT,
                                                 short* __restrict__ woT) {
  __shared__ float tile[32][33];
  int z = blockIdx.z;
  const float* w = (z == 0) ? w0 : (z == 1) ? w1 : (z == 2) ? w2 : w3;
  short* wt = (z == 3) ? woT : wqkvT + (size_t)z * 2048 * 2048;
  int n0 = blockIdx.x * 32, k0 = blockIdx.y * 32;
  int tx = threadIdx.x & 31, ty = threadIdx.x >> 5;
#pragma unroll
  for (int j = 0; j < 4; ++j) {
    int k = ty * 4 + j;
    tile[k][tx] = w[(size_t)(k0 + k) * CCn + n0 + tx];
  }
  __syncthreads();
#pragma unroll
  for (int j = 0; j < 4; ++j) {
    int n = ty * 4 + j;
    wt[(size_t)(n0 + n) * CCn + k0 + tx] = bf16_of(tile[tx][n]);
  }
}

// ---------------- V transpose: qkv[B*T][6144] bf16 (V at col 4096) -> Vt[B*H][D][T] ----
__global__ __launch_bounds__(256) void k_vtrans(const short* __restrict__ src,
                                                short* __restrict__ dst) {
  __shared__ short tile[32][33];
  int bh = blockIdx.y, b = bh >> 4, h = bh & 15;
  int dt = blockIdx.x & 3, tt = blockIdx.x >> 2;
  int tx = threadIdx.x & 31, ty = threadIdx.x >> 5;
  const short* sp = src + ((size_t)(b * TT + tt * 32)) * NQKV + 4096 + h * DD + dt * 32;
#pragma unroll
  for (int j = 0; j < 4; ++j) {
    int tr = ty * 4 + j;
    tile[tr][tx] = sp[(size_t)tr * NQKV + tx];
  }
  __syncthreads();
  short* dp = dst + ((size_t)(bh * DD + dt * 32)) * TT + tt * 32;
#pragma unroll
  for (int j = 0; j < 4; ++j) {
    int dr = ty * 4 + j;
    dp[(size_t)dr * TT + tx] = tile[tx][dr];
  }
}

// ---------------- RoPE (Q and K in one launch, y-indexed) ----------------
__global__ __launch_bounds__(256) void k_rope2(const short* __restrict__ qkv,
                                               const float* __restrict__ cosT,
                                               const float* __restrict__ sinT,
                                               short* __restrict__ Qb,
                                               short* __restrict__ Kb, float kmul) {
  int which = blockIdx.y;
  int coff = which << 11;
  short* dstb = which ? Kb : Qb;
  float mul = which ? kmul : 1.0f;
  int idx = blockIdx.x * 256 + threadIdx.x;  // B*T*H*16
  int i4 = (idx & 15) * 4;
  int h = (idx >> 4) & 15;
  int t = (idx >> 8) & 2047;
  int b = idx >> 19;
  const short* row = qkv + ((size_t)(b * TT + t)) * NQKV + coff + h * DD;
  s16x4 v0 = *(const s16x4*)(row + i4);
  s16x4 v1 = *(const s16x4*)(row + i4 + 64);
  f32x4 c4 = *(const f32x4*)(cosT + t * 64 + i4);
  f32x4 s4 = *(const f32x4*)(sinT + t * 64 + i4);
  s16x4 o0, o1;
#pragma unroll
  for (int j = 0; j < 4; ++j) {
    float a = f_of_bf16(v0[j]), bb = f_of_bf16(v1[j]);
    o0[j] = bf16_of((a * c4[j] - bb * s4[j]) * mul);
    o1[j] = bf16_of((bb * c4[j] + a * s4[j]) * mul);
  }
  short* orow = dstb + ((size_t)((b * HH + h) * TT + t)) * DD;
  *(s16x4*)(orow + i4) = o0;
  *(s16x4*)(orow + i4 + 64) = o1;
}

// ------- 8-phase GEMM, BM=128: C[M][N] = A[M][K] x Bt[N][K], bf16 in -------
// (unchanged from R6 — see R6 header comment for schedule derivation)
template <int WNF, bool BF16OUT>
__global__ __launch_bounds__(512) void k_g8(const short* __restrict__ A,
                                            const short* __restrict__ Bt,
                                            void* __restrict__ Cout,
                                            int M, int N, int K) {
  constexpr int BN = WNF * 64;
  constexpr int AHS = 128 * 32;  // shorts per A half-slot
  constexpr int BHS = BN * 32;   // shorts per B half-slot
  constexpr int NBL = BN / 128;  // gloads/thread per B half
  constexpr int WNH = WNF / 2;
  __shared__ short smem[4 * AHS + 4 * BHS];
  const int tid = threadIdx.x, wid = tid >> 6, lane = tid & 63;
  const int wm = wid >> 2, wn = wid & 3;
  const int lr = lane & 15, lk = lane >> 4;
  const int swz = (lk ^ ((lr >> 1) & 3)) * 8;

  // bijective XCD swizzle (m204)
  int nwg = gridDim.x, orig = blockIdx.x;
  int xcd = orig & 7, bidx = orig >> 3;
  int q = nwg >> 3, rmd = nwg & 7;
  int wg = (xcd < rmd) ? (xcd * (q + 1) + bidx)
                       : (rmd * (q + 1) + (xcd - rmd) * q + bidx);
  const int NBM = M >> 7;
  const int m0 = (wg % NBM) * 128, n0 = (wg / NBM) * BN;

  auto stageA = [&](int buf, int ks, int kt) {
    int row = tid >> 2;
    int cc = (tid & 3) ^ ((row >> 1) & 3);
    lds_load16(A + (size_t)(m0 + row) * K + kt * 64 + ks * 32 + cc * 8,
               smem + buf * 2 * AHS + ks * AHS + tid * 8);
  };
  auto stageB = [&](int buf, int ks, int kt) {
#pragma unroll
    for (int l = 0; l < NBL; ++l) {
      int lin = l * 512 + tid;
      int row = lin >> 2;
      int cc = (lin & 3) ^ ((row >> 1) & 3);
      lds_load16(Bt + (size_t)(n0 + row) * K + kt * 64 + ks * 32 + cc * 8,
                 smem + 4 * AHS + buf * 2 * BHS + ks * BHS + lin * 8);
    }
  };

  s16x8 af[4], bfr[WNH];
  f32x4 acc[4][WNF] = {};

#define LDA(BUF, KS)                                                           \
  _Pragma("unroll") for (int i = 0; i < 4; ++i) af[i] =                        \
      *(const s16x8*)(smem + (BUF) * 2 * AHS + (KS) * AHS +                    \
                      (wm * 64 + i * 16 + lr) * 32 + swz);
#define LDB(BUF, KS, NH)                                                       \
  _Pragma("unroll") for (int j = 0; j < WNH; ++j) bfr[j] =                     \
      *(const s16x8*)(smem + 4 * AHS + (BUF) * 2 * BHS + (KS) * BHS +          \
                      (wn * (WNF * 16) + ((NH) * WNH + j) * 16 + lr) * 32 +    \
                      swz);
#define BAR_MFMA(NH)                                                           \
  __builtin_amdgcn_s_barrier();                                                \
  asm volatile("s_waitcnt lgkmcnt(0)" ::: "memory");                           \
  __builtin_amdgcn_s_setprio(1);                                               \
  _Pragma("unroll") for (int i = 0; i < 4; ++i)                                \
      _Pragma("unroll") for (int j = 0; j < WNH; ++j)                          \
      acc[i][(NH) * WNH + j] = __builtin_amdgcn_mfma_f32_16x16x32_bf16(        \
          af[i], bfr[j], acc[i][(NH) * WNH + j], 0, 0, 0);                     \
  __builtin_amdgcn_s_setprio(0);
#define VMW(cond, NN)                                                          \
  if (cond) { asm volatile("s_waitcnt vmcnt(%0)" ::"i"(NN) : "memory"); }      \
  else      { asm volatile("s_waitcnt vmcnt(0)" ::: "memory"); }

  const int nk = K >> 6, niter = nk >> 1;
  stageA(0, 0, 0); stageB(0, 0, 0);
  stageA(0, 1, 0); stageB(0, 1, 0);
  stageA(1, 0, 1); stageB(1, 0, 1);
  asm volatile("s_waitcnt vmcnt(%0)" ::"i"(1 + NBL) : "memory");
  __builtin_amdgcn_s_barrier();

#pragma unroll 1
  for (int it = 0; it < niter; ++it) {
    const int kt1 = 2 * it + 1, kt2 = 2 * it + 2, kt3 = 2 * it + 3;
    const bool s2 = kt2 < nk, s3 = kt3 < nk;
    // ph1 (b0,k0,n0)
    LDA(0, 0); LDB(0, 0, 0);
    stageA(1, 1, kt1); stageB(1, 1, kt1);
    BAR_MFMA(0);
    __builtin_amdgcn_s_barrier();
    // ph2 (b0,k0,n1)
    LDB(0, 0, 1);
    if (s2) stageA(0, 0, kt2);
    BAR_MFMA(1);
    __builtin_amdgcn_s_barrier();
    // ph3 (b0,k1,n0)
    LDA(0, 1); LDB(0, 1, 0);
    if (s2) stageB(0, 0, kt2);
    BAR_MFMA(0);
    __builtin_amdgcn_s_barrier();
    // ph4 (b0,k1,n1)
    LDB(0, 1, 1);
    if (s2) stageA(0, 1, kt2);
    BAR_MFMA(1);
    VMW(s2, 2 + NBL);
    __builtin_amdgcn_s_barrier();
    // ph5 (b1,k0,n0)
    LDA(1, 0); LDB(1, 0, 0);
    if (s2) stageB(0, 1, kt2);
    BAR_MFMA(0);
    __builtin_amdgcn_s_barrier();
    // ph6 (b1,k0,n1)
    LDB(1, 0, 1);
    if (s3) stageA(1, 0, kt3);
    BAR_MFMA(1);
    __builtin_amdgcn_s_barrier();
    // ph7 (b1,k1,n0)
    LDA(1, 1); LDB(1, 1, 0);
    if (s3) stageB(1, 0, kt3);
    BAR_MFMA(0);
    __builtin_amdgcn_s_barrier();
    // ph8 (b1,k1,n1)
    LDB(1, 1, 1);
    BAR_MFMA(1);
    VMW(s3, 1 + NBL);
    __builtin_amdgcn_s_barrier();
  }
#undef LDA
#undef LDB
#undef BAR_MFMA
#undef VMW

#pragma unroll
  for (int i = 0; i < 4; ++i)
#pragma unroll
    for (int j = 0; j < WNF; ++j) {
      int row0 = m0 + wm * 64 + i * 16 + lk * 4;
      int col = n0 + wn * (WNF * 16) + j * 16 + lr;
#pragma unroll
      for (int rr = 0; rr < 4; ++rr) {
        if (BF16OUT)
          ((short*)Cout)[(size_t)(row0 + rr) * N + col] = bf16_of(acc[i][j][rr]);
        else
          ((float*)Cout)[(size_t)(row0 + rr) * N + col] = acc[i][j][rr];
      }
    }
}

// ---------------- Flash attention (R7: counted-vmcnt pipeline) ----------------
// grid (8, B*H), 512 thr = 8 waves; block bx pairs q-tiles {bx, 15-bx} (128
// rows) -> 34 kv-tiles/block. K,V TRIPLE-buffered (prefetch distance 2 iters
// covers ~900cy HBM). Raw s_barrier + counted vmcnt; never vmcnt(0) mid-loop.
// Per iter kt: QK^T(Ks[kt%3]) -> softmax (Ps within-wave) -> PV(Vs[kt%3]) ->
// B1 -> stage kt+3 into (kt%3) -> {vm(8) | vm(4) | vm(0)} -> B2.
// Waits: steady vm(8) drains kt+1's 4 loads (kt+2,kt+3 = 8 remain);
// kt+3==nkt: vm(4) drains kt+1 (kt+2 remains); later: vm(0).
// V swizzle g(d)=(d&7)^((d>>3)&1): lanes d,d+8 land on different chunks ->
// PV reads max 2-way bank aliased (free), fixing the 5.9M-conflict hotspot.
__global__ __launch_bounds__(512) void k_attn(const short* __restrict__ Qb,
                                              const short* __restrict__ Kb,
                                              const short* __restrict__ Vt,
                                              short* __restrict__ yb) {
  __shared__ short Ks[3][64 * 128];  // 16 KB each
  __shared__ short Vs[3][128 * 64];  // 16 KB each
  __shared__ short Ps[8][16 * 72];   // 18 KB
  const int tid = threadIdx.x, wid = tid >> 6, lane = tid & 63;
  const int lr = lane & 15, lk = lane >> 4;
  const int bh = blockIdx.y, bx = blockIdx.x;
  const size_t baseQK = (size_t)bh * TT * DD;
  const int b = bh >> 4, h = bh & 15;

  auto stageK = [&](int bi, int kt2) {
#pragma unroll
    for (int it = 0; it < 2; ++it) {
      int ch = it * 512 + tid;
      int r = ch >> 4, cc = ch & 15;
      int cs = cc ^ (r & 7);
      lds_load16(Kb + baseQK + (size_t)(kt2 * 64 + r) * DD + cs * 8,
                 &Ks[bi][(size_t)(it * 512 + (tid & ~63)) * 8]);
    }
  };
  auto stageV = [&](int bi, int kt2) {
#pragma unroll
    for (int it = 0; it < 2; ++it) {
      int ch = it * 512 + tid;
      int d = ch >> 3, kc = ch & 7;
      int cs = kc ^ ((d & 7) ^ ((d >> 3) & 1));
      lds_load16(Vt + baseQK + (size_t)d * TT + kt2 * 64 + cs * 8,
                 &Vs[bi][(size_t)(it * 512 + (tid & ~63)) * 8]);
    }
  };

#pragma unroll 1
  for (int pass = 0; pass < 2; ++pass) {
    const int qt = pass ? (15 - bx) : bx;
    const int q0 = qt * 128;
    const int qg = q0 + wid * 16 + lr;
    s16x8 qf[4];
#pragma unroll
    for (int ds = 0; ds < 4; ++ds)
      qf[ds] = *(const s16x8*)(Qb + baseQK + (size_t)qg * DD + (ds * 4 + lk) * 8);

    float mrun = -3.0e38f, lrun = 0.f;
    f32x4 yacc[8] = {};

    const int nkt = 2 * qt + 2;
    stageK(0, 0); stageV(0, 0);
    stageK(1, 1); stageV(1, 1);
    if (nkt > 2) {
      stageK(2, 2); stageV(2, 2);
      asm volatile("s_waitcnt vmcnt(8)" ::: "memory");
    } else {
      asm volatile("s_waitcnt vmcnt(4)" ::: "memory");
    }
    __builtin_amdgcn_s_barrier();

#pragma unroll 1
    for (int kt = 0; kt < nkt; ++kt) {
      const int buf = kt - (kt / 3) * 3;  // kt % 3
      // ---- QK^T: S^T[64kv][16q] from Ks[buf] ----
      f32x4 sf[4] = {};
#pragma unroll
      for (int sub = 0; sub < 4; ++sub) {
        int kr = sub * 16 + lr;
#pragma unroll
        for (int ds = 0; ds < 4; ++ds) {
          int cc = (ds * 4 + lk) ^ (kr & 7);
          s16x8 kf = *(const s16x8*)(&Ks[buf][kr * 128 + cc * 8]);
          sf[sub] = __builtin_amdgcn_mfma_f32_16x16x32_bf16(kf, qf[ds], sf[sub], 0, 0, 0);
        }
      }
      const int kvbase = kt * 64;
      if (kvbase + 63 > q0 + wid * 16) {
#pragma unroll
        for (int sub = 0; sub < 4; ++sub)
#pragma unroll
          for (int r = 0; r < 4; ++r) {
            int kv = kvbase + sub * 16 + lk * 4 + r;
            if (kv > qg) sf[sub][r] = -3.0e38f;
          }
      }
      float tmax = -3.0e38f;
#pragma unroll
      for (int sub = 0; sub < 4; ++sub)
#pragma unroll
        for (int r = 0; r < 4; ++r) tmax = fmaxf(tmax, sf[sub][r]);
      tmax = fmaxf(tmax, __shfl_xor(tmax, 16, 64));
      tmax = fmaxf(tmax, __shfl_xor(tmax, 32, 64));
      if (!__all(tmax <= mrun + 11.0f)) {
        float mnew = fmaxf(mrun, tmax);
        float alpha = ex2(mrun - mnew);
        mrun = mnew;
        lrun *= alpha;
        float ar[4];
#pragma unroll
        for (int r = 0; r < 4; ++r) ar[r] = __shfl(alpha, lk * 4 + r, 64);
#pragma unroll
        for (int dn = 0; dn < 8; ++dn)
#pragma unroll
          for (int r = 0; r < 4; ++r) yacc[dn][r] *= ar[r];
      }
      float psum = 0.f;
#pragma unroll
      for (int sub = 0; sub < 4; ++sub) {
        s16x4 pq;
#pragma unroll
        for (int r = 0; r < 4; ++r) {
          float p = ex2(sf[sub][r] - mrun);
          psum += p;
          pq[r] = bf16_of(p);
        }
        *(s16x4*)(&Ps[wid][lr * 72 + sub * 16 + lk * 4]) = pq;
      }
      psum += __shfl_xor(psum, 16, 64);
      psum += __shfl_xor(psum, 32, 64);
      lrun += psum;
      // ---- PV: y[16q][128d] += P[16q][64kv] x V[64kv][128d] (Vs[buf]) ----
      s16x8 pf0 = *(const s16x8*)(&Ps[wid][lr * 72 + lk * 8]);
      s16x8 pf1 = *(const s16x8*)(&Ps[wid][lr * 72 + 32 + lk * 8]);
#pragma unroll
      for (int dn = 0; dn < 8; ++dn) {
        int d = dn * 16 + lr;
        int g = (d & 7) ^ ((d >> 3) & 1);
        s16x8 vf0 = *(const s16x8*)(&Vs[buf][d * 64 + (lk ^ g) * 8]);
        yacc[dn] = __builtin_amdgcn_mfma_f32_16x16x32_bf16(pf0, vf0, yacc[dn], 0, 0, 0);
        s16x8 vf1 = *(const s16x8*)(&Vs[buf][d * 64 + ((4 + lk) ^ g) * 8]);
        yacc[dn] = __builtin_amdgcn_mfma_f32_16x16x32_bf16(pf1, vf1, yacc[dn], 0, 0, 0);
      }
      __builtin_amdgcn_s_barrier();  // B1: all waves done reading buf
      if (kt + 3 < nkt) {
        stageK(buf, kt + 3); stageV(buf, kt + 3);
        asm volatile("s_waitcnt vmcnt(8)" ::: "memory");
      } else if (kt + 3 == nkt) {
        asm volatile("s_waitcnt vmcnt(4)" ::: "memory");
      } else {
        asm volatile("s_waitcnt vmcnt(0)" ::: "memory");
      }
      __builtin_amdgcn_s_barrier();  // B2: tile kt+1 landed & visible
    }
    // epilogue: y[q][d] / l[q] -> yb[B][T][C] bf16
    float linv = 1.f / lrun;
    float lr4[4];
#pragma unroll
    for (int r = 0; r < 4; ++r) lr4[r] = __shfl(linv, lk * 4 + r, 64);
#pragma unroll
    for (int dn = 0; dn < 8; ++dn)
#pragma unroll
      for (int r = 0; r < 4; ++r) {
        int t = q0 + wid * 16 + lk * 4 + r;
        int c = h * DD + dn * 16 + lr;
        yb[((size_t)(b * TT + t)) * CCn + c] = bf16_of(yacc[dn][r] * lr4[r]);
      }
  }
}

extern "C" void kernel_launch(void* const* d_in, const int* in_sizes, int n_in,
                              void* d_out, int out_size, void* d_ws, size_t ws_size,
                              hipStream_t stream) {
  const float* x = (const float*)d_in[0];
  const float* wq = (const float*)d_in[1];
  const float* wk = (const float*)d_in[2];
  const float* wv = (const float*)d_in[3];
  const float* wo = (const float*)d_in[4];
  float* out = (float*)d_out;
  char* ws = (char*)d_ws;

  short* xb = (short*)(ws + 0);                 // 16,777,216
  short* wqkvT = (short*)(ws + 16777216);       // [6144][2048] bf16
  short* woT = (short*)(ws + 41943040);
  short* qkv = (short*)(ws + 50331648);         // [4096][6144] bf16
  short* yb = (short*)(ws + 50331648);          // alias: reused after qkv consumed
  short* Qb = (short*)(ws + 100663296);
  short* Kb = (short*)(ws + 117440512);
  short* Vt = (short*)(ws + 134217728);
  float* cosT = (float*)(ws + 150994944);
  float* sinT = (float*)(ws + 151519232);

  const float kmul = 1.4426950408889634f / sqrtf(128.0f);  // log2e / sqrt(D)

  k_tables<<<512, 256, 0, stream>>>(cosT, sinT);
  k_cast_x<<<8192, 256, 0, stream>>>(x, xb);
  k_wtrans4<<<dim3(64, 64, 4), 256, 0, stream>>>(wq, wk, wv, wo, wqkvT, woT);

  // fused QKV GEMM: 128x384 tiles, grid 32x16 = 512 blocks (2 perfect rounds)
  k_g8<6, true><<<512, 512, 0, stream>>>(xb, wqkvT, qkv, MMr, NQKV, CCn);

  k_rope2<<<dim3(4096, 2), 256, 0, stream>>>(qkv, cosT, sinT, Qb, Kb, kmul);
  k_vtrans<<<dim3(256, 32), 256, 0, stream>>>(qkv, Vt);

  k_attn<<<dim3(8, 32), 512, 0, stream>>>(Qb, Kb, Vt, yb);

  // output GEMM: 128x256 tiles, grid 32x8 = 256 blocks (1 perfect round)
  k_g8<4, false><<<256, 512, 0, stream>>>(yb, woT, out, MMr, CCn, CCn);
}

// Round 8
// 385.242 us; speedup vs baseline: 1.0430x; 1.0430x over previous
//
#include <hip/hip_runtime.h>
#include <hip/hip_bf16.h>
#include <math.h>

// LlamaStyleAttention: B=2, T=2048, C=2048, H=16, D=128, fp32 in/out.
// R8: attn XCD-affinity swizzle — 1D grid, xcd=bid&7, all 8 q-blocks of a
//     head on one XCD (4 heads/XCD = 4MB KV = L2-resident). K/V L2 fill
//     drops 8x -> ~90MB total traffic. Everything else frozen from R7.

#define TT 2048
#define CCn 2048
#define HH 16
#define DD 128
#define MMr 4096   // B*T
#define NQKV 6144  // 3*C

typedef __attribute__((ext_vector_type(8))) short s16x8;
typedef __attribute__((ext_vector_type(4))) short s16x4;
typedef __attribute__((ext_vector_type(4))) float f32x4;

__device__ __forceinline__ short bf16_of(float f) {
  unsigned u = __float_as_uint(f);
  unsigned r = u + 0x7fffu + ((u >> 16) & 1u);
  return (short)(r >> 16);
}
__device__ __forceinline__ float f_of_bf16(short s) {
  return __uint_as_float(((unsigned)(unsigned short)s) << 16);
}
__device__ __forceinline__ float ex2(float x) { return exp2f(x); }

__device__ __forceinline__ void lds_load16(const void* g, void* l) {
  __builtin_amdgcn_global_load_lds((__attribute__((address_space(1))) void*)g,
                                   (__attribute__((address_space(3))) void*)l,
                                   16, 0, 0);
}

// ---------------- cos/sin tables: [T][64] fp32 ----------------
__global__ __launch_bounds__(256) void k_tables(float* __restrict__ cosT,
                                                float* __restrict__ sinT) {
  int idx = blockIdx.x * 256 + threadIdx.x;
  int t = idx >> 6, i = idx & 63;
  float inv = powf(10000.0f, -(float)i * (1.0f / 64.0f));
  float f = (float)t * inv;
  cosT[idx] = cosf(f);
  sinT[idx] = sinf(f);
}

// ---------------- x fp32 -> bf16 ----------------
__global__ __launch_bounds__(256) void k_cast_x(const float* __restrict__ x,
                                                short* __restrict__ xb) {
  int i = blockIdx.x * 256 + threadIdx.x;
  f32x4 v = ((const f32x4*)x)[i];
  s16x4 o;
#pragma unroll
  for (int j = 0; j < 4; ++j) o[j] = bf16_of(v[j]);
  ((s16x4*)xb)[i] = o;
}

// ------------- weight transpose+cast (all 4 weights, z-indexed) -------------
__global__ __launch_bounds__(256) void k_wtrans4(const float* __restrict__ w0,
                                                 const float* __restrict__ w1,
                                                 const float* __restrict__ w2,
                                                 const float* __restrict__ w3,
                                                 short* __restrict__ wqkvT,
                                                 short* __restrict__ woT) {
  __shared__ float tile[32][33];
  int z = blockIdx.z;
  const float* w = (z == 0) ? w0 : (z == 1) ? w1 : (z == 2) ? w2 : w3;
  short* wt = (z == 3) ? woT : wqkvT + (size_t)z * 2048 * 2048;
  int n0 = blockIdx.x * 32, k0 = blockIdx.y * 32;
  int tx = threadIdx.x & 31, ty = threadIdx.x >> 5;
#pragma unroll
  for (int j = 0; j < 4; ++j) {
    int k = ty * 4 + j;
    tile[k][tx] = w[(size_t)(k0 + k) * CCn + n0 + tx];
  }
  __syncthreads();
#pragma unroll
  for (int j = 0; j < 4; ++j) {
    int n = ty * 4 + j;
    wt[(size_t)(n0 + n) * CCn + k0 + tx] = bf16_of(tile[tx][n]);
  }
}

// ---------------- V transpose: qkv[B*T][6144] bf16 (V at col 4096) -> Vt[B*H][D][T] ----
__global__ __launch_bounds__(256) void k_vtrans(const short* __restrict__ src,
                                                short* __restrict__ dst) {
  __shared__ short tile[32][33];
  int bh = blockIdx.y, b = bh >> 4, h = bh & 15;
  int dt = blockIdx.x & 3, tt = blockIdx.x >> 2;
  int tx = threadIdx.x & 31, ty = threadIdx.x >> 5;
  const short* sp = src + ((size_t)(b * TT + tt * 32)) * NQKV + 4096 + h * DD + dt * 32;
#pragma unroll
  for (int j = 0; j < 4; ++j) {
    int tr = ty * 4 + j;
    tile[tr][tx] = sp[(size_t)tr * NQKV + tx];
  }
  __syncthreads();
  short* dp = dst + ((size_t)(bh * DD + dt * 32)) * TT + tt * 32;
#pragma unroll
  for (int j = 0; j < 4; ++j) {
    int dr = ty * 4 + j;
    dp[(size_t)dr * TT + tx] = tile[tx][dr];
  }
}

// ---------------- RoPE (Q and K in one launch, y-indexed) ----------------
__global__ __launch_bounds__(256) void k_rope2(const short* __restrict__ qkv,
                                               const float* __restrict__ cosT,
                                               const float* __restrict__ sinT,
                                               short* __restrict__ Qb,
                                               short* __restrict__ Kb, float kmul) {
  int which = blockIdx.y;
  int coff = which << 11;
  short* dstb = which ? Kb : Qb;
  float mul = which ? kmul : 1.0f;
  int idx = blockIdx.x * 256 + threadIdx.x;  // B*T*H*16
  int i4 = (idx & 15) * 4;
  int h = (idx >> 4) & 15;
  int t = (idx >> 8) & 2047;
  int b = idx >> 19;
  const short* row = qkv + ((size_t)(b * TT + t)) * NQKV + coff + h * DD;
  s16x4 v0 = *(const s16x4*)(row + i4);
  s16x4 v1 = *(const s16x4*)(row + i4 + 64);
  f32x4 c4 = *(const f32x4*)(cosT + t * 64 + i4);
  f32x4 s4 = *(const f32x4*)(sinT + t * 64 + i4);
  s16x4 o0, o1;
#pragma unroll
  for (int j = 0; j < 4; ++j) {
    float a = f_of_bf16(v0[j]), bb = f_of_bf16(v1[j]);
    o0[j] = bf16_of((a * c4[j] - bb * s4[j]) * mul);
    o1[j] = bf16_of((bb * c4[j] + a * s4[j]) * mul);
  }
  short* orow = dstb + ((size_t)((b * HH + h) * TT + t)) * DD;
  *(s16x4*)(orow + i4) = o0;
  *(s16x4*)(orow + i4 + 64) = o1;
}

// ------- 8-phase GEMM, BM=128: C[M][N] = A[M][K] x Bt[N][K], bf16 in -------
// (unchanged from R6 — see R6 header comment for schedule derivation)
template <int WNF, bool BF16OUT>
__global__ __launch_bounds__(512) void k_g8(const short* __restrict__ A,
                                            const short* __restrict__ Bt,
                                            void* __restrict__ Cout,
                                            int M, int N, int K) {
  constexpr int BN = WNF * 64;
  constexpr int AHS = 128 * 32;  // shorts per A half-slot
  constexpr int BHS = BN * 32;   // shorts per B half-slot
  constexpr int NBL = BN / 128;  // gloads/thread per B half
  constexpr int WNH = WNF / 2;
  __shared__ short smem[4 * AHS + 4 * BHS];
  const int tid = threadIdx.x, wid = tid >> 6, lane = tid & 63;
  const int wm = wid >> 2, wn = wid & 3;
  const int lr = lane & 15, lk = lane >> 4;
  const int swz = (lk ^ ((lr >> 1) & 3)) * 8;

  // bijective XCD swizzle (m204)
  int nwg = gridDim.x, orig = blockIdx.x;
  int xcd = orig & 7, bidx = orig >> 3;
  int q = nwg >> 3, rmd = nwg & 7;
  int wg = (xcd < rmd) ? (xcd * (q + 1) + bidx)
                       : (rmd * (q + 1) + (xcd - rmd) * q + bidx);
  const int NBM = M >> 7;
  const int m0 = (wg % NBM) * 128, n0 = (wg / NBM) * BN;

  auto stageA = [&](int buf, int ks, int kt) {
    int row = tid >> 2;
    int cc = (tid & 3) ^ ((row >> 1) & 3);
    lds_load16(A + (size_t)(m0 + row) * K + kt * 64 + ks * 32 + cc * 8,
               smem + buf * 2 * AHS + ks * AHS + tid * 8);
  };
  auto stageB = [&](int buf, int ks, int kt) {
#pragma unroll
    for (int l = 0; l < NBL; ++l) {
      int lin = l * 512 + tid;
      int row = lin >> 2;
      int cc = (lin & 3) ^ ((row >> 1) & 3);
      lds_load16(Bt + (size_t)(n0 + row) * K + kt * 64 + ks * 32 + cc * 8,
                 smem + 4 * AHS + buf * 2 * BHS + ks * BHS + lin * 8);
    }
  };

  s16x8 af[4], bfr[WNH];
  f32x4 acc[4][WNF] = {};

#define LDA(BUF, KS)                                                           \
  _Pragma("unroll") for (int i = 0; i < 4; ++i) af[i] =                        \
      *(const s16x8*)(smem + (BUF) * 2 * AHS + (KS) * AHS +                    \
                      (wm * 64 + i * 16 + lr) * 32 + swz);
#define LDB(BUF, KS, NH)                                                       \
  _Pragma("unroll") for (int j = 0; j < WNH; ++j) bfr[j] =                     \
      *(const s16x8*)(smem + 4 * AHS + (BUF) * 2 * BHS + (KS) * BHS +          \
                      (wn * (WNF * 16) + ((NH) * WNH + j) * 16 + lr) * 32 +    \
                      swz);
#define BAR_MFMA(NH)                                                           \
  __builtin_amdgcn_s_barrier();                                                \
  asm volatile("s_waitcnt lgkmcnt(0)" ::: "memory");                           \
  __builtin_amdgcn_s_setprio(1);                                               \
  _Pragma("unroll") for (int i = 0; i < 4; ++i)                                \
      _Pragma("unroll") for (int j = 0; j < WNH; ++j)                          \
      acc[i][(NH) * WNH + j] = __builtin_amdgcn_mfma_f32_16x16x32_bf16(        \
          af[i], bfr[j], acc[i][(NH) * WNH + j], 0, 0, 0);                     \
  __builtin_amdgcn_s_setprio(0);
#define VMW(cond, NN)                                                          \
  if (cond) { asm volatile("s_waitcnt vmcnt(%0)" ::"i"(NN) : "memory"); }      \
  else      { asm volatile("s_waitcnt vmcnt(0)" ::: "memory"); }

  const int nk = K >> 6, niter = nk >> 1;
  stageA(0, 0, 0); stageB(0, 0, 0);
  stageA(0, 1, 0); stageB(0, 1, 0);
  stageA(1, 0, 1); stageB(1, 0, 1);
  asm volatile("s_waitcnt vmcnt(%0)" ::"i"(1 + NBL) : "memory");
  __builtin_amdgcn_s_barrier();

#pragma unroll 1
  for (int it = 0; it < niter; ++it) {
    const int kt1 = 2 * it + 1, kt2 = 2 * it + 2, kt3 = 2 * it + 3;
    const bool s2 = kt2 < nk, s3 = kt3 < nk;
    // ph1 (b0,k0,n0)
    LDA(0, 0); LDB(0, 0, 0);
    stageA(1, 1, kt1); stageB(1, 1, kt1);
    BAR_MFMA(0);
    __builtin_amdgcn_s_barrier();
    // ph2 (b0,k0,n1)
    LDB(0, 0, 1);
    if (s2) stageA(0, 0, kt2);
    BAR_MFMA(1);
    __builtin_amdgcn_s_barrier();
    // ph3 (b0,k1,n0)
    LDA(0, 1); LDB(0, 1, 0);
    if (s2) stageB(0, 0, kt2);
    BAR_MFMA(0);
    __builtin_amdgcn_s_barrier();
    // ph4 (b0,k1,n1)
    LDB(0, 1, 1);
    if (s2) stageA(0, 1, kt2);
    BAR_MFMA(1);
    VMW(s2, 2 + NBL);
    __builtin_amdgcn_s_barrier();
    // ph5 (b1,k0,n0)
    LDA(1, 0); LDB(1, 0, 0);
    if (s2) stageB(0, 1, kt2);
    BAR_MFMA(0);
    __builtin_amdgcn_s_barrier();
    // ph6 (b1,k0,n1)
    LDB(1, 0, 1);
    if (s3) stageA(1, 0, kt3);
    BAR_MFMA(1);
    __builtin_amdgcn_s_barrier();
    // ph7 (b1,k1,n0)
    LDA(1, 1); LDB(1, 1, 0);
    if (s3) stageB(1, 0, kt3);
    BAR_MFMA(0);
    __builtin_amdgcn_s_barrier();
    // ph8 (b1,k1,n1)
    LDB(1, 1, 1);
    BAR_MFMA(1);
    VMW(s3, 1 + NBL);
    __builtin_amdgcn_s_barrier();
  }
#undef LDA
#undef LDB
#undef BAR_MFMA
#undef VMW

#pragma unroll
  for (int i = 0; i < 4; ++i)
#pragma unroll
    for (int j = 0; j < WNF; ++j) {
      int row0 = m0 + wm * 64 + i * 16 + lk * 4;
      int col = n0 + wn * (WNF * 16) + j * 16 + lr;
#pragma unroll
      for (int rr = 0; rr < 4; ++rr) {
        if (BF16OUT)
          ((short*)Cout)[(size_t)(row0 + rr) * N + col] = bf16_of(acc[i][j][rr]);
        else
          ((float*)Cout)[(size_t)(row0 + rr) * N + col] = acc[i][j][rr];
      }
    }
}

// ---------------- Flash attention (R8: XCD-affinity) ----------------
// 1D grid 256 blocks, 512 thr = 8 waves. Dispatch round-robins XCD = bid&7;
// we invert it so one XCD owns all 8 q-pair blocks of a head: bh =
// ((j&3)<<3)|xcd, qp = j>>2 (j = bid>>3). 4 heads/XCD -> 4MB K+V = L2-
// resident; K/V fetched into L2 once per head instead of 8x.
// Inner loop unchanged from R7 (triple-buffered K/V, counted vmcnt).
__global__ __launch_bounds__(512) void k_attn(const short* __restrict__ Qb,
                                              const short* __restrict__ Kb,
                                              const short* __restrict__ Vt,
                                              short* __restrict__ yb) {
  __shared__ short Ks[3][64 * 128];  // 16 KB each
  __shared__ short Vs[3][128 * 64];  // 16 KB each
  __shared__ short Ps[8][16 * 72];   // 18 KB
  const int tid = threadIdx.x, wid = tid >> 6, lane = tid & 63;
  const int lr = lane & 15, lk = lane >> 4;
  const int bid = blockIdx.x;
  const int xcd = bid & 7, j = bid >> 3;
  const int bh = ((j & 3) << 3) | xcd;  // 4 heads per XCD
  const int qp = j >> 2;                // q-pair index 0..7
  const size_t baseQK = (size_t)bh * TT * DD;
  const int b = bh >> 4, h = bh & 15;

  auto stageK = [&](int bi, int kt2) {
#pragma unroll
    for (int it = 0; it < 2; ++it) {
      int ch = it * 512 + tid;
      int r = ch >> 4, cc = ch & 15;
      int cs = cc ^ (r & 7);
      lds_load16(Kb + baseQK + (size_t)(kt2 * 64 + r) * DD + cs * 8,
                 &Ks[bi][(size_t)(it * 512 + (tid & ~63)) * 8]);
    }
  };
  auto stageV = [&](int bi, int kt2) {
#pragma unroll
    for (int it = 0; it < 2; ++it) {
      int ch = it * 512 + tid;
      int d = ch >> 3, kc = ch & 7;
      int cs = kc ^ ((d & 7) ^ ((d >> 3) & 1));
      lds_load16(Vt + baseQK + (size_t)d * TT + kt2 * 64 + cs * 8,
                 &Vs[bi][(size_t)(it * 512 + (tid & ~63)) * 8]);
    }
  };

#pragma unroll 1
  for (int pass = 0; pass < 2; ++pass) {
    const int qt = pass ? (15 - qp) : qp;
    const int q0 = qt * 128;
    const int qg = q0 + wid * 16 + lr;
    s16x8 qf[4];
#pragma unroll
    for (int ds = 0; ds < 4; ++ds)
      qf[ds] = *(const s16x8*)(Qb + baseQK + (size_t)qg * DD + (ds * 4 + lk) * 8);

    float mrun = -3.0e38f, lrun = 0.f;
    f32x4 yacc[8] = {};

    const int nkt = 2 * qt + 2;
    stageK(0, 0); stageV(0, 0);
    stageK(1, 1); stageV(1, 1);
    if (nkt > 2) {
      stageK(2, 2); stageV(2, 2);
      asm volatile("s_waitcnt vmcnt(8)" ::: "memory");
    } else {
      asm volatile("s_waitcnt vmcnt(4)" ::: "memory");
    }
    __builtin_amdgcn_s_barrier();

#pragma unroll 1
    for (int kt = 0; kt < nkt; ++kt) {
      const int buf = kt - (kt / 3) * 3;  // kt % 3
      // ---- QK^T: S^T[64kv][16q] from Ks[buf] ----
      f32x4 sf[4] = {};
#pragma unroll
      for (int sub = 0; sub < 4; ++sub) {
        int kr = sub * 16 + lr;
#pragma unroll
        for (int ds = 0; ds < 4; ++ds) {
          int cc = (ds * 4 + lk) ^ (kr & 7);
          s16x8 kf = *(const s16x8*)(&Ks[buf][kr * 128 + cc * 8]);
          sf[sub] = __builtin_amdgcn_mfma_f32_16x16x32_bf16(kf, qf[ds], sf[sub], 0, 0, 0);
        }
      }
      const int kvbase = kt * 64;
      if (kvbase + 63 > q0 + wid * 16) {
#pragma unroll
        for (int sub = 0; sub < 4; ++sub)
#pragma unroll
          for (int r = 0; r < 4; ++r) {
            int kv = kvbase + sub * 16 + lk * 4 + r;
            if (kv > qg) sf[sub][r] = -3.0e38f;
          }
      }
      float tmax = -3.0e38f;
#pragma unroll
      for (int sub = 0; sub < 4; ++sub)
#pragma unroll
        for (int r = 0; r < 4; ++r) tmax = fmaxf(tmax, sf[sub][r]);
      tmax = fmaxf(tmax, __shfl_xor(tmax, 16, 64));
      tmax = fmaxf(tmax, __shfl_xor(tmax, 32, 64));
      if (!__all(tmax <= mrun + 11.0f)) {
        float mnew = fmaxf(mrun, tmax);
        float alpha = ex2(mrun - mnew);
        mrun = mnew;
        lrun *= alpha;
        float ar[4];
#pragma unroll
        for (int r = 0; r < 4; ++r) ar[r] = __shfl(alpha, lk * 4 + r, 64);
#pragma unroll
        for (int dn = 0; dn < 8; ++dn)
#pragma unroll
          for (int r = 0; r < 4; ++r) yacc[dn][r] *= ar[r];
      }
      float psum = 0.f;
#pragma unroll
      for (int sub = 0; sub < 4; ++sub) {
        s16x4 pq;
#pragma unroll
        for (int r = 0; r < 4; ++r) {
          float p = ex2(sf[sub][r] - mrun);
          psum += p;
          pq[r] = bf16_of(p);
        }
        *(s16x4*)(&Ps[wid][lr * 72 + sub * 16 + lk * 4]) = pq;
      }
      psum += __shfl_xor(psum, 16, 64);
      psum += __shfl_xor(psum, 32, 64);
      lrun += psum;
      // ---- PV: y[16q][128d] += P[16q][64kv] x V[64kv][128d] (Vs[buf]) ----
      s16x8 pf0 = *(const s16x8*)(&Ps[wid][lr * 72 + lk * 8]);
      s16x8 pf1 = *(const s16x8*)(&Ps[wid][lr * 72 + 32 + lk * 8]);
#pragma unroll
      for (int dn = 0; dn < 8; ++dn) {
        int d = dn * 16 + lr;
        int g = (d & 7) ^ ((d >> 3) & 1);
        s16x8 vf0 = *(const s16x8*)(&Vs[buf][d * 64 + (lk ^ g) * 8]);
        yacc[dn] = __builtin_amdgcn_mfma_f32_16x16x32_bf16(pf0, vf0, yacc[dn], 0, 0, 0);
        s16x8 vf1 = *(const s16x8*)(&Vs[buf][d * 64 + ((4 + lk) ^ g) * 8]);
        yacc[dn] = __builtin_amdgcn_mfma_f32_16x16x32_bf16(pf1, vf1, yacc[dn], 0, 0, 0);
      }
      __builtin_amdgcn_s_barrier();  // B1: all waves done reading buf
      if (kt + 3 < nkt) {
        stageK(buf, kt + 3); stageV(buf, kt + 3);
        asm volatile("s_waitcnt vmcnt(8)" ::: "memory");
      } else if (kt + 3 == nkt) {
        asm volatile("s_waitcnt vmcnt(4)" ::: "memory");
      } else {
        asm volatile("s_waitcnt vmcnt(0)" ::: "memory");
      }
      __builtin_amdgcn_s_barrier();  // B2: tile kt+1 landed & visible
    }
    // epilogue: y[q][d] / l[q] -> yb[B][T][C] bf16
    float linv = 1.f / lrun;
    float lr4[4];
#pragma unroll
    for (int r = 0; r < 4; ++r) lr4[r] = __shfl(linv, lk * 4 + r, 64);
#pragma unroll
    for (int dn = 0; dn < 8; ++dn)
#pragma unroll
      for (int r = 0; r < 4; ++r) {
        int t = q0 + wid * 16 + lk * 4 + r;
        int c = h * DD + dn * 16 + lr;
        yb[((size_t)(b * TT + t)) * CCn + c] = bf16_of(yacc[dn][r] * lr4[r]);
      }
  }
}

extern "C" void kernel_launch(void* const* d_in, const int* in_sizes, int n_in,
                              void* d_out, int out_size, void* d_ws, size_t ws_size,
                              hipStream_t stream) {
  const float* x = (const float*)d_in[0];
  const float* wq = (const float*)d_in[1];
  const float* wk = (const float*)d_in[2];
  const float* wv = (const float*)d_in[3];
  const float* wo = (const float*)d_in[4];
  float* out = (float*)d_out;
  char* ws = (char*)d_ws;

  short* xb = (short*)(ws + 0);                 // 16,777,216
  short* wqkvT = (short*)(ws + 16777216);       // [6144][2048] bf16
  short* woT = (short*)(ws + 41943040);
  short* qkv = (short*)(ws + 50331648);         // [4096][6144] bf16
  short* yb = (short*)(ws + 50331648);          // alias: reused after qkv consumed
  short* Qb = (short*)(ws + 100663296);
  short* Kb = (short*)(ws + 117440512);
  short* Vt = (short*)(ws + 134217728);
  float* cosT = (float*)(ws + 150994944);
  float* sinT = (float*)(ws + 151519232);

  const float kmul = 1.4426950408889634f / sqrtf(128.0f);  // log2e / sqrt(D)

  k_tables<<<512, 256, 0, stream>>>(cosT, sinT);
  k_cast_x<<<8192, 256, 0, stream>>>(x, xb);
  k_wtrans4<<<dim3(64, 64, 4), 256, 0, stream>>>(wq, wk, wv, wo, wqkvT, woT);

  // fused QKV GEMM: 128x384 tiles, grid 32x16 = 512 blocks (2 perfect rounds)
  k_g8<6, true><<<512, 512, 0, stream>>>(xb, wqkvT, qkv, MMr, NQKV, CCn);

  k_rope2<<<dim3(4096, 2), 256, 0, stream>>>(qkv, cosT, sinT, Qb, Kb, kmul);
  k_vtrans<<<dim3(256, 32), 256, 0, stream>>>(qkv, Vt);

  k_attn<<<256, 512, 0, stream>>>(Qb, Kb, Vt, yb);

  // output GEMM: 128x256 tiles, grid 32x8 = 256 blocks (1 perfect round)
  k_g8<4, false><<<256, 512, 0, stream>>>(yb, woT, out, MMr, CCn, CCn);
}